// Round 2
// 462.702 us; speedup vs baseline: 1.1972x; 1.1972x over previous
//
#include <hip/hip_runtime.h>
#include <hip/hip_bf16.h>
#include <type_traits>

// Problem constants
#define Bb  2
#define Ss  2048
#define Hh  2048
#define NHh 16
#define HDd 128
#define Mm  (Bb * Ss)   // 4096 rows

typedef __attribute__((ext_vector_type(8))) short short8;  // 8 bf16 (4 VGPRs)
typedef __attribute__((ext_vector_type(4))) float f32x4;   // MFMA accumulator

#if __has_builtin(__builtin_amdgcn_exp2f)
#define EXPFN(x) __builtin_amdgcn_exp2f(x)
#define QSCALE 0.12751744416668577f   /* (1/sqrt(128)) * log2(e), folded into Q */
#else
#define EXPFN(x) __expf(x)
#define QSCALE 0.08838834764831845f   /* 1/sqrt(128) folded into Q */
#endif

__device__ __forceinline__ float bf2f(unsigned short u) {
    unsigned int x = ((unsigned int)u) << 16;
    return __builtin_bit_cast(float, x);
}
__device__ __forceinline__ unsigned short f2bf(float f) {
    unsigned int x = __builtin_bit_cast(unsigned int, f);
    x += 0x7fffu + ((x >> 16) & 1u);   // RNE
    return (unsigned short)(x >> 16);
}

// ---------------------------------------------------------------- cast fp32->bf16
__global__ __launch_bounds__(256) void cast_f32_to_bf16(const float* __restrict__ in,
                                                        unsigned short* __restrict__ out, int n) {
    int i = (blockIdx.x * 256 + threadIdx.x) * 4;
    if (i + 3 < n) {
        float4 f = *(const float4*)(in + i);
        ushort4 o;
        o.x = f2bf(f.x); o.y = f2bf(f.y); o.z = f2bf(f.z); o.w = f2bf(f.w);
        *(ushort4*)(out + i) = o;
    }
}

// ---------------------------------------------------------------- GEMM: C = A * Bt^T + bias
// A [M][K] bf16 (K-contig), Bt [N][K] bf16 (K-contig), C [M][N] (OutT = float or bf16)
// m97 structure: 128x128 tile, BK=64, 4 waves, global_load_lds width=16, 16x16x32 MFMA.
template <typename OutT>
__global__ __launch_bounds__(256) void gemm_bt(const unsigned short* __restrict__ A,
                                               const unsigned short* __restrict__ Bt,
                                               const float* __restrict__ bias,
                                               OutT* __restrict__ C,
                                               int M, int N, int K) {
    __shared__ unsigned short As[128 * 64];
    __shared__ unsigned short Bs[128 * 64];
    const int tid  = threadIdx.x;
    const int lane = tid & 63;
    const int wave = tid >> 6;
    const int q4 = lane >> 4, l15 = lane & 15;
    const int m0 = blockIdx.y * 128, n0 = blockIdx.x * 128;
    const int wm = (wave >> 1) * 64, wn = (wave & 1) * 64;

    f32x4 acc[4][4] = {};

    for (int k0 = 0; k0 < K; k0 += 64) {
#pragma unroll
        for (int t = 0; t < 4; ++t) {
            const int chunk = t * 256 + tid;           // 0..1023, lane-contiguous per wave
            const int row = chunk >> 3, c8 = chunk & 7;   // K-tile = 64 shorts = 8 x 16B chunks
            const unsigned short* ga = A  + (size_t)(m0 + row) * K + (k0 + c8 * 8);
            const unsigned short* gb = Bt + (size_t)(n0 + row) * K + (k0 + c8 * 8);
            __builtin_amdgcn_global_load_lds((const __attribute__((address_space(1))) unsigned int*)ga,
                                             (__attribute__((address_space(3))) unsigned int*)(As + chunk * 8),
                                             16, 0, 0);
            __builtin_amdgcn_global_load_lds((const __attribute__((address_space(1))) unsigned int*)gb,
                                             (__attribute__((address_space(3))) unsigned int*)(Bs + chunk * 8),
                                             16, 0, 0);
        }
        __syncthreads();   // drains vmcnt before LDS consumption
#pragma unroll
        for (int kk = 0; kk < 2; ++kk) {
            short8 a[4], b[4];
#pragma unroll
            for (int i = 0; i < 4; ++i)
                a[i] = *(const short8*)(As + (wm + i * 16 + l15) * 64 + kk * 32 + q4 * 8);
#pragma unroll
            for (int j = 0; j < 4; ++j)
                b[j] = *(const short8*)(Bs + (wn + j * 16 + l15) * 64 + kk * 32 + q4 * 8);
#pragma unroll
            for (int i = 0; i < 4; ++i)
#pragma unroll
                for (int j = 0; j < 4; ++j)
                    acc[i][j] = __builtin_amdgcn_mfma_f32_16x16x32_bf16(a[i], b[j], acc[i][j], 0, 0, 0);
        }
        __syncthreads();
    }

    // C/D layout: col = lane&15, row = (lane>>4)*4 + r   [m89/m91 verified]
#pragma unroll
    for (int i = 0; i < 4; ++i) {
#pragma unroll
        for (int j = 0; j < 4; ++j) {
            const int col = n0 + wn + j * 16 + l15;
            const float bv = bias[col];
            const size_t base = (size_t)(m0 + wm + i * 16 + q4 * 4) * N + col;
#pragma unroll
            for (int r = 0; r < 4; ++r) {
                float v = acc[i][j][r] + bv;
                if constexpr (std::is_same_v<OutT, float>)
                    C[base + (size_t)r * N] = v;
                else
                    C[base + (size_t)r * N] = f2bf(v);
            }
        }
    }
}

// ---------------------------------------------------------------- RoPE + repack Q,K to [B*NH][S][HD]
// Q is pre-scaled by QSCALE (softmax scale, and log2e if exp2 path).
__global__ __launch_bounds__(256) void rope_repack(const unsigned short* __restrict__ qkv, // [B][S][3H] bf16
                                                   const float* __restrict__ cosp,         // [S][HD]
                                                   const float* __restrict__ sinp,
                                                   unsigned short* __restrict__ Qr,
                                                   unsigned short* __restrict__ Kr) {
    const int s = blockIdx.x, b = blockIdx.y, tid = threadIdx.x;
    const unsigned short* base = qkv + (size_t)(b * Ss + s) * (3 * Hh);
#pragma unroll
    for (int t = 0; t < 4; ++t) {
        const int p = t * 256 + tid;     // 0..1023 : 16 heads x 64 pairs
        const int h = p >> 6, d = p & 63;
        const float c  = cosp[s * HDd + d];   // cos[d] == cos[d+64]
        const float sn = sinp[s * HDd + d];
        const size_t o = ((size_t)(b * NHh + h) * Ss + s) * HDd;
        float q1 = bf2f(base[h * HDd + d]), q2 = bf2f(base[h * HDd + d + 64]);
        Qr[o + d]      = f2bf((q1 * c - q2 * sn) * QSCALE);
        Qr[o + d + 64] = f2bf((q2 * c + q1 * sn) * QSCALE);
        float k1 = bf2f(base[Hh + h * HDd + d]), k2 = bf2f(base[Hh + h * HDd + d + 64]);
        Kr[o + d]      = f2bf(k1 * c - k2 * sn);
        Kr[o + d + 64] = f2bf(k2 * c + k1 * sn);
    }
}

// ---------------------------------------------------------------- V transpose: qkv V-part -> Vt [B*NH][HD][S]
// 64x64 tile per block, XOR-swizzled LDS (conflict-free b128 writes, 2-way scalar reads).
__global__ __launch_bounds__(256) void v_transpose(const unsigned short* __restrict__ qkv,
                                                   unsigned short* __restrict__ Vt) {
    __shared__ unsigned short T[64 * 64];
    const int tid = threadIdx.x;
    const int st = blockIdx.x;        // s-tile (64 rows)
    const int dt = blockIdx.y;        // d-tile (64 cols)
    const int bh = blockIdx.z;
    const int b = bh >> 4, h = bh & 15;
#pragma unroll
    for (int it = 0; it < 2; ++it) {
        const int chunk = it * 256 + tid;          // 0..511
        const int row = chunk >> 3, c8 = chunk & 7;
        const unsigned short* src = qkv + ((size_t)(b * Ss + st * 64 + row)) * (3 * Hh)
                                        + 2 * Hh + h * HDd + dt * 64 + c8 * 8;
        uint4 v = *(const uint4*)src;
        *(uint4*)(T + row * 64 + ((c8 ^ (row & 7)) * 8)) = v;   // element (row,col) at col-chunk c^(row&7)
    }
    __syncthreads();
#pragma unroll
    for (int it = 0; it < 2; ++it) {
        const int chunk = it * 256 + tid;          // 0..511
        const int drow = chunk & 63;               // lane-major over d -> 2-way LDS reads
        const int c8s = chunk >> 6;                // 16B chunk along s
        ushort4 lo, hi;
        unsigned short tmp[8];
#pragma unroll
        for (int j = 0; j < 8; ++j) {
            const int sl = c8s * 8 + j;
            tmp[j] = T[sl * 64 + (((drow >> 3) ^ (sl & 7)) * 8) + (drow & 7)];
        }
        lo.x = tmp[0]; lo.y = tmp[1]; lo.z = tmp[2]; lo.w = tmp[3];
        hi.x = tmp[4]; hi.y = tmp[5]; hi.z = tmp[6]; hi.w = tmp[7];
        unsigned short* dst = Vt + ((size_t)bh * HDd + dt * 64 + drow) * Ss + st * 64 + c8s * 8;
        *(ushort4*)(dst)     = lo;
        *(ushort4*)(dst + 4) = hi;
    }
}

// ---------------------------------------------------------------- flash attention (causal, FA2-paired)
// Block handles Q-tiles qA=blockIdx.x and qB=31-qA (64 rows each).
// R0 change: 8 waves/block (512 thr). Waves 0-3 own qA's four 16-row strips,
// waves 4-7 own qB's. Same paired-uniform work per BLOCK (33 tile-computes),
// but per-wave serial path halves and waves/CU doubles (8 -> 16 at 2 blocks/CU).
// Wave i -> SIMD i&3, so every SIMD hosts one A-wave + one B-wave: when the
// A-wave runs out of causal range it idles and the B-wave keeps the SIMD fed.
// KV tile = 64 keys staged once per block, shared by both q-tiles.
// Fragment-major LDS (conflict-free, verified r4: 43.8M -> 0.5M conflicts).
__global__ __launch_bounds__(512, 4) void attn_fwd(const unsigned short* __restrict__ Qr,
                                                   const unsigned short* __restrict__ Kr,
                                                   const unsigned short* __restrict__ Vt,
                                                   unsigned short* __restrict__ AO) {  // [B][S][H] bf16
    __shared__ unsigned short Ks[16 * 64 * 8];    // 16 segs (g,kc) x 64 lanes x 8 bf16  (16 KB)
    __shared__ unsigned short VtS[16 * 64 * 8];   // 16 segs (n,ks) x 64 lanes x 8 bf16  (16 KB)
    __shared__ unsigned short Ps[8][16 * 72];     // per-wave P round-trip (18.4 KB)
    const int tid = threadIdx.x;
    const int lane = tid & 63, wave = tid >> 6;   // wave 0..7
    const int q4 = lane >> 4, l15 = lane & 15;
    const int qA = (int)blockIdx.x;               // 0..15
    const int qB = 31 - qA;                       // mirror tile (FA2 causal balancing)
    const int bh = blockIdx.y;
    const int b = bh >> 4, h = bh & 15;
    const unsigned short* Qh  = Qr + (size_t)bh * Ss * HDd;
    const unsigned short* Kh  = Kr + (size_t)bh * Ss * HDd;
    const unsigned short* Vth = Vt + (size_t)bh * HDd * Ss;

    // this wave's 16 query rows: waves 0-3 -> qA strips, waves 4-7 -> qB strips
    const int mt = wave >> 2;                     // 0 = A-tile, 1 = B-tile
    const int wg = wave & 3;
    const int s0 = (mt ? qB : qA) * 64 + wg * 16;

    // Q fragments (A-layout: m=lane&15, k=quad*8+j), 4 k-chunks of 32 over HD=128
    short8 qf[4];
#pragma unroll
    for (int kc = 0; kc < 4; ++kc)
        qf[kc] = *(const short8*)(Qh + (size_t)(s0 + l15) * HDd + kc * 32 + q4 * 8);

    f32x4 o_acc[8] = {};
    float m_i[4], l_i[4];
#pragma unroll
    for (int r = 0; r < 4; ++r) { m_i[r] = -1e30f; l_i[r] = 0.f; }

    const int kv_end = qB * 64 + 64;   // qB > qA always; covers both tiles' needs
    for (int t0 = 0; t0 < kv_end; t0 += 64) {
        // stage K tile fragment-major: seg s=(g,kc); lane (q4,l15) gathers K[t0+g*16+l15][kc*32+q4*8]
#pragma unroll
        for (int it = 0; it < 2; ++it) {
            const int s = it * 8 + wave;
            const int g = s >> 2, kc = s & 3;
            const unsigned short* gk = Kh + (size_t)(t0 + g * 16 + l15) * HDd + kc * 32 + q4 * 8;
            __builtin_amdgcn_global_load_lds((const __attribute__((address_space(1))) unsigned int*)gk,
                                             (__attribute__((address_space(3))) unsigned int*)(Ks + (s * 64 + lane) * 8),
                                             16, 0, 0);
        }
        // stage Vt tile fragment-major: seg s=(n,ks); lane (q4,l15) gathers Vt[n*16+l15][t0+ks*32+q4*8]
#pragma unroll
        for (int it = 0; it < 2; ++it) {
            const int s = it * 8 + wave;
            const int n = s >> 1, ks = s & 1;
            const unsigned short* gv = Vth + (size_t)(n * 16 + l15) * Ss + t0 + ks * 32 + q4 * 8;
            __builtin_amdgcn_global_load_lds((const __attribute__((address_space(1))) unsigned int*)gv,
                                             (__attribute__((address_space(3))) unsigned int*)(VtS + (s * 64 + lane) * 8),
                                             16, 0, 0);
        }
        __syncthreads();

        if (t0 <= s0 + 15) {   // wave-uniform: tile has >=1 unmasked key for these rows
            // scores (pre-scaled Q): 4 key groups of 16; skip fully-masked groups
            float sv[4][4];
#pragma unroll
            for (int g = 0; g < 4; ++g)
#pragma unroll
                for (int r = 0; r < 4; ++r) sv[g][r] = -1e30f;
#pragma unroll
            for (int g = 0; g < 4; ++g) {
                if (t0 + g * 16 <= s0 + 15) {
                    f32x4 scg = {};
#pragma unroll
                    for (int kc = 0; kc < 4; ++kc) {
                        short8 kf = *(const short8*)(Ks + ((g * 4 + kc) * 64 + lane) * 8);
                        scg = __builtin_amdgcn_mfma_f32_16x16x32_bf16(qf[kc], kf, scg, 0, 0, 0);
                    }
                    const int key = t0 + g * 16 + l15;
#pragma unroll
                    for (int r = 0; r < 4; ++r)
                        sv[g][r] = (key <= s0 + q4 * 4 + r) ? scg[r] : -1e30f;
                }
            }
            float mnew[4], alpha[4], sm[4];
            bool need = false;
#pragma unroll
            for (int r = 0; r < 4; ++r) {
                float mx = fmaxf(fmaxf(sv[0][r], sv[1][r]), fmaxf(sv[2][r], sv[3][r]));
#pragma unroll
                for (int off = 1; off < 16; off <<= 1)
                    mx = fmaxf(mx, __shfl_xor(mx, off, 16));
                mnew[r]  = fmaxf(m_i[r], mx);
                need = need || (mnew[r] > m_i[r]);
                alpha[r] = EXPFN(m_i[r] - mnew[r]);
                m_i[r] = mnew[r];
            }
            float p[4][4];
#pragma unroll
            for (int g = 0; g < 4; ++g)
#pragma unroll
                for (int r = 0; r < 4; ++r)
                    p[g][r] = EXPFN(sv[g][r] - mnew[r]);
#pragma unroll
            for (int r = 0; r < 4; ++r) {
                float s2 = (p[0][r] + p[1][r]) + (p[2][r] + p[3][r]);
#pragma unroll
                for (int off = 1; off < 16; off <<= 1)
                    s2 += __shfl_xor(s2, off, 16);
                sm[r] = s2;
            }
            if (__any(need)) {    // alpha==1 exactly when no max moved -> skip is exact
#pragma unroll
                for (int r = 0; r < 4; ++r) l_i[r] *= alpha[r];
#pragma unroll
                for (int n = 0; n < 8; ++n)
#pragma unroll
                    for (int r = 0; r < 4; ++r)
                        o_acc[n][r] *= alpha[r];
            }
#pragma unroll
            for (int r = 0; r < 4; ++r) l_i[r] += sm[r];

            // P: C-layout -> per-wave LDS -> A-layout (within-wave, no barrier)
            unsigned short* Pw = &Ps[wave][0];
#pragma unroll
            for (int g = 0; g < 4; ++g)
#pragma unroll
                for (int r = 0; r < 4; ++r)
                    Pw[(q4 * 4 + r) * 72 + g * 16 + l15] = f2bf(p[g][r]);

            // PV: B-frags fragment-major; skip fully-masked key-halves
#pragma unroll
            for (int ks = 0; ks < 2; ++ks) {
                if (t0 + ks * 32 <= s0 + 15) {
                    short8 pfk = *(const short8*)(Pw + l15 * 72 + ks * 32 + q4 * 8);
#pragma unroll
                    for (int n = 0; n < 8; ++n) {
                        short8 vf = *(const short8*)(VtS + ((n * 2 + ks) * 64 + lane) * 8);
                        o_acc[n] = __builtin_amdgcn_mfma_f32_16x16x32_bf16(pfk, vf, o_acc[n], 0, 0, 0);
                    }
                }
            }
        }
        __syncthreads();   // all waves done with Ks/VtS before next stage
    }

    // normalize + write [B][S][H] bf16 (direct A-matrix for out-projection GEMM)
    float inv[4];
#pragma unroll
    for (int r = 0; r < 4; ++r) inv[r] = 1.f / l_i[r];
#pragma unroll
    for (int n = 0; n < 8; ++n)
#pragma unroll
        for (int r = 0; r < 4; ++r) {
            const int query = s0 + q4 * 4 + r;
            AO[((size_t)(b * Ss + query)) * Hh + h * HDd + n * 16 + l15] = f2bf(o_acc[n][r] * inv[r]);
        }
}

// ---------------------------------------------------------------- host
extern "C" void kernel_launch(void* const* d_in, const int* in_sizes, int n_in,
                              void* d_out, int out_size, void* d_ws, size_t ws_size,
                              hipStream_t stream) {
    const float* X    = (const float*)d_in[0];
    const float* cosp = (const float*)d_in[1];
    const float* sinp = (const float*)d_in[2];
    const float* Wqkv = (const float*)d_in[3];
    const float* bqkv = (const float*)d_in[4];
    const float* Wout = (const float*)d_in[5];
    const float* bout = (const float*)d_in[6];
    float* out = (float*)d_out;

    char* ws = (char*)d_ws;
    size_t off = 0;
    auto carve = [&](size_t bytes) { void* p = ws + off; off += bytes; return p; };
    unsigned short* Xb    = (unsigned short*)carve((size_t)Mm * Hh * 2);        // 16 MB
    unsigned short* Wqkvb = (unsigned short*)carve((size_t)3 * Hh * Hh * 2);    // 24 MB
    unsigned short* Woutb = (unsigned short*)carve((size_t)Hh * Hh * 2);        //  8 MB
    unsigned short* QKVb  = (unsigned short*)carve((size_t)Mm * 3 * Hh * 2);    // 48 MB
    unsigned short* Qr    = (unsigned short*)carve((size_t)Mm * Hh * 2);        // 16 MB
    unsigned short* Kr    = (unsigned short*)carve((size_t)Mm * Hh * 2);        // 16 MB
    unsigned short* Vt    = (unsigned short*)carve((size_t)Mm * Hh * 2);        // 16 MB (transposed per head)
    unsigned short* AOb   = (unsigned short*)carve((size_t)Mm * Hh * 2);        // 16 MB

    cast_f32_to_bf16<<<(Mm * Hh) / 1024, 256, 0, stream>>>(X, Xb, Mm * Hh);
    cast_f32_to_bf16<<<(3 * Hh * Hh) / 1024, 256, 0, stream>>>(Wqkv, Wqkvb, 3 * Hh * Hh);
    cast_f32_to_bf16<<<(Hh * Hh) / 1024, 256, 0, stream>>>(Wout, Woutb, Hh * Hh);

    gemm_bt<unsigned short><<<dim3((3 * Hh) / 128, Mm / 128), 256, 0, stream>>>(
        Xb, Wqkvb, bqkv, QKVb, Mm, 3 * Hh, Hh);

    rope_repack<<<dim3(Ss, Bb), 256, 0, stream>>>(QKVb, cosp, sinp, Qr, Kr);

    v_transpose<<<dim3(Ss / 64, HDd / 64, Bb * NHh), 256, 0, stream>>>(QKVb, Vt);

    attn_fwd<<<dim3(Ss / 128, Bb * NHh), 512, 0, stream>>>(Qr, Kr, Vt, AOb);

    gemm_bt<float><<<dim3(Hh / 128, Mm / 128), 256, 0, stream>>>(
        AOb, Woutb, bout, out, Mm, Hh, Hh);
}